// Round 17
// baseline (75.511 us; speedup 1.0000x reference)
//
#include <hip/hip_runtime.h>
#include <hip/hip_bf16.h>

// 2D DCT-II (4096x4096 fp32).  Round 17:
//   K1  = dct_rows4 v2: trip-1 (Makhoul LDS distribute) DELETED -- threads
//         load v[512u+64v+l] directly from global (ix = u<4 ? 2n : 8191-2n;
//         complementary halves are L1 hits, block working set = 32KB = L1).
//         Trips alternate pane A (xchg 4096) / pane B (pad-65 4160) -> all
//         WAR hazards covered by the previous trip's barrier: 4 barriers
//         (was 9).  LDS 66KB -> 2 blocks/CU.
//   K2a = cooperative column step 1 (unchanged)
//   K2b = linearity-form column step 2 (unchanged)
// Plan: K1(x->out) ; K2a(out->ws) ; K2b(ws->out).  d_ws needs 64 MB.

#define L 4096

__device__ __forceinline__ float2 cmul(float2 a, float2 b) {
    return make_float2(a.x * b.x - a.y * b.y, a.x * b.y + a.y * b.x);
}

__device__ __forceinline__ void bfly4(float2& x0, float2& x1, float2& x2, float2& x3) {
    float t0x = x0.x + x2.x, t0y = x0.y + x2.y;
    float t1x = x0.x - x2.x, t1y = x0.y - x2.y;
    float t2x = x1.x + x3.x, t2y = x1.y + x3.y;
    float t3x = x1.x - x3.x, t3y = x1.y - x3.y;
    x0 = make_float2(t0x + t2x, t0y + t2y);
    x1 = make_float2(t1x + t3y, t1y - t3x);   // t1 + (-i)*t3
    x2 = make_float2(t0x - t2x, t0y - t2y);
    x3 = make_float2(t1x - t3y, t1y + t3x);   // t1 + (+i)*t3
}

#define FOR8(X) X(0) X(1) X(2) X(3) X(4) X(5) X(6) X(7)

// 8-point DFT on named regs P0..P7, natural in -> natural out (DIT):
#define FFT8N(P) \
  bfly4(P##0, P##2, P##4, P##6); \
  bfly4(P##1, P##3, P##5, P##7); \
  { float2 e1_=P##2, e2_=P##4, e3_=P##6, o0_=P##1, o1_=P##3, o2_=P##5, o3_=P##7; \
    o1_ = cmul(o1_, make_float2(0.70710678118654752f, -0.70710678118654752f)); \
    o2_ = make_float2(o2_.y, -o2_.x); \
    o3_ = cmul(o3_, make_float2(-0.70710678118654752f, -0.70710678118654752f)); \
    float2 e0_=P##0; \
    P##0 = make_float2(e0_.x+o0_.x, e0_.y+o0_.y); \
    P##4 = make_float2(e0_.x-o0_.x, e0_.y-o0_.y); \
    P##1 = make_float2(e1_.x+o1_.x, e1_.y+o1_.y); \
    P##5 = make_float2(e1_.x-o1_.x, e1_.y-o1_.y); \
    P##2 = make_float2(e2_.x+o2_.x, e2_.y+o2_.y); \
    P##6 = make_float2(e2_.x-o2_.x, e2_.y-o2_.y); \
    P##3 = make_float2(e3_.x+o3_.x, e3_.y+o3_.y); \
    P##7 = make_float2(e3_.x-o3_.x, e3_.y-o3_.y); }

#define TWCHAIN(P, W) { float2 f_ = W; \
    P##1 = cmul(P##1, f_); f_ = cmul(f_, W); \
    P##2 = cmul(P##2, f_); f_ = cmul(f_, W); \
    P##3 = cmul(P##3, f_); f_ = cmul(f_, W); \
    P##4 = cmul(P##4, f_); f_ = cmul(f_, W); \
    P##5 = cmul(P##5, f_); f_ = cmul(f_, W); \
    P##6 = cmul(P##6, f_); f_ = cmul(f_, W); \
    P##7 = cmul(P##7, f_); }

// ---------------- K1: cooperative row DCT, v2 ----------------
// Thread (l = lane 0..63, v = wave 0..7).  n = 64a + b, a = 8u+v, b = l.
// Pane A = xch[0,4096) (xchg layout), pane B = xch[4096, 8256) (pad-65).
__global__ __launch_bounds__(512)
void dct_rows4_kernel(const float* __restrict__ in, float* __restrict__ out) {
    __shared__ float2 xch[8256];            // 66,048 B -> 2 blocks/CU
    const int l = threadIdx.x & 63;
    const int v = threadIdx.x >> 6;
    const int r0 = blockIdx.x * 2;
    const float* rowA = in + (size_t)r0 * L;
    const float* rowB = rowA + L;

    // direct Makhoul load: g_u = (vA[n], vB[n]), n = 512u+64v+l
#define LD(u) float2 g##u; { \
        const int n = 512*u + 64*v + l; \
        const int ix = (u < 4) ? (2*n) : (8191 - 2*n); \
        g##u = make_float2(rowA[ix], rowB[ix]); }
    FOR8(LD)
#undef LD

    // ---- FFT64 over a (a = 8u+v), fixed b = l ----
    FFT8N(g)
#define W2(t) xch[512*v + 64*t + l] = g##t;
    FOR8(W2)
#undef W2
    __syncthreads();                        // B1
#define R2(vv) g##vv = xch[512*vv + 64*v + l];
    FOR8(R2)
#undef R2

    float2 wv; __sincosf((float)v * -0.09817477042468103f, &wv.y, &wv.x); // -2pi v/64
    TWCHAIN(g, wv)
    FFT8N(g)                                // -> H[q = 8s+v][b = l] in g_s

    // mid twiddle W4096^{l*q}: anchor e^{-2pi l v/4096}, step e^{-pi l/256}
    float2 mw, ms;
    __sincosf((float)(l * v) * -1.5339807878856412e-3f, &mw.y, &mw.x);
    __sincosf((float)l * -1.2271846303085130e-2f, &ms.y, &ms.x);
#define W3(s) { g##s = cmul(g##s, mw); xch[4096 + 520*s + 65*v + l] = g##s; mw = cmul(mw, ms); }
    FOR8(W3)
#undef W3
    __syncthreads();                        // B2
    // redistribute: role q' = l; f_u = H[l][8u+v] at B[65*l + 8u + v]
#define R3(u) g##u = xch[4096 + 65*l + 8*u + v];
    FOR8(R3)
#undef R3

    // ---- FFT64 over b (b = 8u+v), fixed q = l ----
    FFT8N(g)
#define W4(t) xch[512*v + 64*t + l] = g##t;
    FOR8(W4)
#undef W4
    __syncthreads();                        // B3
#define R4(vv) g##vv = xch[512*vv + 64*v + l];
    FOR8(R4)
#undef R4

    TWCHAIN(g, wv)
    FFT8N(g)                                // -> X[512s + 64v + l] in g_s

    // trip: pane B [p][q] (pad 65), p = 8s+v, q = l
#define W5(s) xch[4096 + 520*s + 65*v + l] = g##s;
    FOR8(W5)
#undef W5
    __syncthreads();                        // B4

    // epilogue: conj-split + expk.  k = 512s + 64v + l, partner m = (4096-k)&4095
    float* outA = out + (size_t)r0 * L;
    float* outB = outA + L;
    float2 e; __sincosf((float)(64*v + l) * 3.8349519697141029e-4f, &e.y, &e.x); // pi k0/8192
    const float2 ST = make_float2(0.98078528040323045f, 0.19509032201612827f);   // e^{i pi/16}
#define EP5(s) { \
        const int k = 512*s + 64*v + l; \
        const int m = (4096 - k) & 4095; \
        float2 Zk = g##s; \
        float2 Zm = xch[4096 + (m >> 6) * 65 + (m & 63)]; \
        float vax = 0.5f*(Zk.x + Zm.x), vay = 0.5f*(Zk.y - Zm.y); \
        float vbx = 0.5f*(Zk.y + Zm.y), vby = 0.5f*(Zm.x - Zk.x); \
        outA[k] = vax*e.x + vay*e.y; \
        outB[k] = vbx*e.x + vby*e.y; \
        e = cmul(e, ST); }
    FOR8(EP5)
#undef EP5
}

// ---------------- K2a: cooperative column pass, step 1 (unchanged) ----------------
__global__ __launch_bounds__(512)
void fft64_col_a2(const float* __restrict__ Y, float* __restrict__ ws) {
    __shared__ float2 xch[4096];            // [v][t][c], 32 KB
    const int c = threadIdx.x & 63;
    const int v = threadIdx.x >> 6;         // 0..7
    const int b = blockIdx.x;               // 0..63
    const int T = blockIdx.y;               // 0..31
    const int ca = T * 128 + c;
    const int cb = ca + 64;

#define LDA(u) float2 g##u; { \
        const int aa = 8 * u + v; \
        const int row = (u < 4) ? (128 * aa + 2 * b) : (8191 - 128 * aa - 2 * b); \
        const float* rp = Y + (size_t)row * L; \
        g##u = make_float2(rp[ca], rp[cb]); }
    FOR8(LDA)
#undef LDA

    FFT8N(g)                                // over u -> G[t][v] in g_t

#define WRA(t) xch[v * 512 + t * 64 + c] = g##t;
    FOR8(WRA)
#undef WRA
    __syncthreads();
#define RDA(vv) g##vv = xch[vv * 512 + v * 64 + c];
    FOR8(RDA)
#undef RDA

    float2 wv; __sincosf((float)v * -0.09817477042468103f, &wv.y, &wv.x); // -2pi v/64
    TWCHAIN(g, wv)

    FFT8N(g)                                // -> Z[q], q = 8s+v, in g_s

    float2 mw, ms;
    __sincosf((float)(b * v) * -1.5339807878856412e-3f, &mw.y, &mw.x);
    __sincosf((float)b * -1.2271846303085130e-2f, &ms.y, &ms.x);   // -pi b/256
    float2* wp = reinterpret_cast<float2*>(ws) + (size_t)b * 2048 + (size_t)T * 64 + c;
#define STA(s) { \
        g##s = cmul(g##s, mw); \
        wp[(size_t)(8 * s + v) * 131072] = g##s; \
        mw = cmul(mw, ms); }
    FOR8(STA)
#undef STA
}

// ---------------- K2b: column pass step 2, linearity form (unchanged) ----------------
__global__ __launch_bounds__(512)
void fft64_col_b3(const float* __restrict__ wsf, float* __restrict__ out) {
    __shared__ float2 xch[8192];            // [0,4096)=X pane, [4096,8192)=G pane
    const int c  = threadIdx.x & 63;
    const int v  = threadIdx.x >> 6;        // 0..7
    const int qa = blockIdx.x;              // 0..31
    const int T  = blockIdx.y;              // 0..31
    const int q  = qa;
    const int q2 = (qa == 0) ? 32 : 64 - qa;

    const float2* wsc = reinterpret_cast<const float2*>(wsf);
    const size_t cbase = (size_t)T * 64 + c;

#define LDH(u) \
    float2 ha##u = wsc[(size_t)q  * 131072 + (size_t)(8*u+v) * 2048 + cbase]; \
    float2 hp##u = wsc[(size_t)q2 * 131072 + (size_t)(8*u+v) * 2048 + cbase];
    FOR8(LDH)
#undef LDH

    float2 wv; __sincosf((float)v * -0.09817477042468103f, &wv.y, &wv.x);

    // ---- FFT64 #1: Gq = FFT64_b(H[q]) ----
    FFT8N(ha)
#define W1(k) xch[v * 512 + k * 64 + c] = ha##k;
    FOR8(W1)
#undef W1
    __syncthreads();                        // bar1
#define DECLG(i) float2 g##i;
    FOR8(DECLG)
#undef DECLG
#define R1b(vv) g##vv = xch[vv * 512 + v * 64 + c];
    FOR8(R1b)
#undef R1b
    TWCHAIN(g, wv)
    FFT8N(g)                                // -> Gq[8a+v] in g_a

#define SV(a) float2 gq##a = g##a; xch[4096 + (8*a + v) * 64 + c] = g##a;
    FOR8(SV)
#undef SV
    __syncthreads();                        // bar2

    // ---- FFT64 #2: Gq2 = FFT64_b(H[q2]) ----
    FFT8N(hp)
#define W2b(k) xch[v * 512 + k * 64 + c] = hp##k;
    FOR8(W2b)
#undef W2b
    __syncthreads();                        // bar3
#define R2b(vv) g##vv = xch[vv * 512 + v * 64 + c];
    FOR8(R2b)
#undef R2b
    TWCHAIN(g, wv)
    FFT8N(g)                                // -> Gq2[8a+v] in g_a
    __syncthreads();                        // bar4
#define W3b(a) xch[(8*a + v) * 64 + c] = g##a;
    FOR8(W3b)
#undef W3b
    __syncthreads();                        // bar5

    const float2 STEP = make_float2(0.98078528040323045f, 0.19509032201612827f); // e^{+i pi/16}
    float2 eq, eq2;
    __sincosf((float)(64 * v + q ) * 3.8349519697141029e-4f, &eq.y,  &eq.x);
    __sincosf((float)(64 * v + q2) * 3.8349519697141029e-4f, &eq2.y, &eq2.x);
    const int colA = T * 128 + c;

#define CMB(a) { \
    const int p_ = 8 * a + v; \
    float2 rq  = (qa == 0) ? xch[4096 + (((64 - p_) & 63) * 64) + c] \
                           : xch[(63 - p_) * 64 + c]; \
    float2 rq2 = (qa == 0) ? xch[(63 - p_) * 64 + c] \
                           : xch[4096 + (63 - p_) * 64 + c]; \
    float FAx = 0.5f * (gq##a.x + rq.x), FAy = 0.5f * (gq##a.y - rq.y); \
    float FBx = 0.5f * (gq##a.y + rq.y), FBy = 0.5f * (rq.x - gq##a.x); \
    size_t rowq = (size_t)(512 * a + 64 * v + q) * L; \
    out[rowq + colA]      = FAx * eq.x + FAy * eq.y; \
    out[rowq + colA + 64] = FBx * eq.x + FBy * eq.y; \
    float GAx = 0.5f * (g##a.x + rq2.x), GAy = 0.5f * (g##a.y - rq2.y); \
    float GBx = 0.5f * (g##a.y + rq2.y), GBy = 0.5f * (rq2.x - g##a.x); \
    size_t rowq2 = (size_t)(512 * a + 64 * v + q2) * L; \
    out[rowq2 + colA]      = GAx * eq2.x + GAy * eq2.y; \
    out[rowq2 + colA + 64] = GBx * eq2.x + GBy * eq2.y; \
    eq = cmul(eq, STEP); eq2 = cmul(eq2, STEP); }
    FOR8(CMB)
#undef CMB
}

extern "C" void kernel_launch(void* const* d_in, const int* in_sizes, int n_in,
                              void* d_out, int out_size, void* d_ws, size_t ws_size,
                              hipStream_t stream) {
    const float* x = (const float*)d_in[0];
    float* out = (float*)d_out;
    float* ws  = (float*)d_ws;   // needs 64 MB

    dct_rows4_kernel<<<L / 2, 512, 0, stream>>>(x, out);        // rows: x -> Y(out)
    fft64_col_a2<<<dim3(64, 32), 512, 0, stream>>>(out, ws);    // Y -> H(ws)
    fft64_col_b3<<<dim3(32, 32), 512, 0, stream>>>(ws, out);    // H -> final(out)
}

// Round 18
// 73.424 us; speedup vs baseline: 1.0284x; 1.0284x over previous
//
#include <hip/hip_runtime.h>
#include <hip/hip_bf16.h>

// 2D DCT-II (4096x4096 fp32).  Round 18:
//   K1  = dct_rows4 v3: direct Makhoul global load (no LDS trip 1, from R17)
//         + SINGLE 33KB pane (4160 float2, from R16) -> 4 blocks/CU restored.
//         7 barriers (R16's 9 minus trip-1's 2).  R17 lesson: occupancy
//         (4 vs 2 blocks/CU) beats barrier count (4 vs 7) in this regime.
//   K2a = cooperative column step 1 (unchanged)
//   K2b = linearity-form column step 2 (unchanged)
// Plan: K1(x->out) ; K2a(out->ws) ; K2b(ws->out).  d_ws needs 64 MB.

#define L 4096

__device__ __forceinline__ float2 cmul(float2 a, float2 b) {
    return make_float2(a.x * b.x - a.y * b.y, a.x * b.y + a.y * b.x);
}

__device__ __forceinline__ void bfly4(float2& x0, float2& x1, float2& x2, float2& x3) {
    float t0x = x0.x + x2.x, t0y = x0.y + x2.y;
    float t1x = x0.x - x2.x, t1y = x0.y - x2.y;
    float t2x = x1.x + x3.x, t2y = x1.y + x3.y;
    float t3x = x1.x - x3.x, t3y = x1.y - x3.y;
    x0 = make_float2(t0x + t2x, t0y + t2y);
    x1 = make_float2(t1x + t3y, t1y - t3x);   // t1 + (-i)*t3
    x2 = make_float2(t0x - t2x, t0y - t2y);
    x3 = make_float2(t1x - t3y, t1y + t3x);   // t1 + (+i)*t3
}

#define FOR8(X) X(0) X(1) X(2) X(3) X(4) X(5) X(6) X(7)

// 8-point DFT on named regs P0..P7, natural in -> natural out (DIT):
#define FFT8N(P) \
  bfly4(P##0, P##2, P##4, P##6); \
  bfly4(P##1, P##3, P##5, P##7); \
  { float2 e1_=P##2, e2_=P##4, e3_=P##6, o0_=P##1, o1_=P##3, o2_=P##5, o3_=P##7; \
    o1_ = cmul(o1_, make_float2(0.70710678118654752f, -0.70710678118654752f)); \
    o2_ = make_float2(o2_.y, -o2_.x); \
    o3_ = cmul(o3_, make_float2(-0.70710678118654752f, -0.70710678118654752f)); \
    float2 e0_=P##0; \
    P##0 = make_float2(e0_.x+o0_.x, e0_.y+o0_.y); \
    P##4 = make_float2(e0_.x-o0_.x, e0_.y-o0_.y); \
    P##1 = make_float2(e1_.x+o1_.x, e1_.y+o1_.y); \
    P##5 = make_float2(e1_.x-o1_.x, e1_.y-o1_.y); \
    P##2 = make_float2(e2_.x+o2_.x, e2_.y+o2_.y); \
    P##6 = make_float2(e2_.x-o2_.x, e2_.y-o2_.y); \
    P##3 = make_float2(e3_.x+o3_.x, e3_.y+o3_.y); \
    P##7 = make_float2(e3_.x-o3_.x, e3_.y-o3_.y); }

#define TWCHAIN(P, W) { float2 f_ = W; \
    P##1 = cmul(P##1, f_); f_ = cmul(f_, W); \
    P##2 = cmul(P##2, f_); f_ = cmul(f_, W); \
    P##3 = cmul(P##3, f_); f_ = cmul(f_, W); \
    P##4 = cmul(P##4, f_); f_ = cmul(f_, W); \
    P##5 = cmul(P##5, f_); f_ = cmul(f_, W); \
    P##6 = cmul(P##6, f_); f_ = cmul(f_, W); \
    P##7 = cmul(P##7, f_); }

// ---------------- K1: cooperative row DCT, v3 ----------------
// Thread (l = lane 0..63, v = wave 0..7).  n = 64a + b, a = 8u+v, b = l.
// Single pane xch[4160]: alternates xchg layout [512v+64t+l] and pad-65
// layout [520s+65v+l] with WAR barriers.
__global__ __launch_bounds__(512)
void dct_rows4_kernel(const float* __restrict__ in, float* __restrict__ out) {
    __shared__ float2 xch[4160];            // 33,280 B -> 4 blocks/CU
    const int l = threadIdx.x & 63;
    const int v = threadIdx.x >> 6;
    const int r0 = blockIdx.x * 2;
    const float* rowA = in + (size_t)r0 * L;
    const float* rowB = rowA + L;

    // direct Makhoul load: g_u = (vA[n], vB[n]), n = 512u+64v+l
#define LD(u) float2 g##u; { \
        const int n = 512*u + 64*v + l; \
        const int ix = (u < 4) ? (2*n) : (8191 - 2*n); \
        g##u = make_float2(rowA[ix], rowB[ix]); }
    FOR8(LD)
#undef LD

    // ---- FFT64 over a (a = 8u+v), fixed b = l ----
    FFT8N(g)
#define W2(t) xch[512*v + 64*t + l] = g##t;
    FOR8(W2)
#undef W2
    __syncthreads();                        // B1
#define R2(vv) g##vv = xch[512*vv + 64*v + l];
    FOR8(R2)
#undef R2
    __syncthreads();                        // B2 (WAR)

    float2 wv; __sincosf((float)v * -0.09817477042468103f, &wv.y, &wv.x); // -2pi v/64
    TWCHAIN(g, wv)
    FFT8N(g)                                // -> H[q = 8s+v][b = l] in g_s

    // mid twiddle W4096^{l*q}: anchor e^{-2pi l v/4096}, step e^{-pi l/256}
    float2 mw, ms;
    __sincosf((float)(l * v) * -1.5339807878856412e-3f, &mw.y, &mw.x);
    __sincosf((float)l * -1.2271846303085130e-2f, &ms.y, &ms.x);
#define W3(s) { g##s = cmul(g##s, mw); xch[520*s + 65*v + l] = g##s; mw = cmul(mw, ms); }
    FOR8(W3)
#undef W3
    __syncthreads();                        // B3
    // redistribute: role q' = l; f_u = H[l][8u+v] at [65*l + 8u + v]
#define R3(u) g##u = xch[65*l + 8*u + v];
    FOR8(R3)
#undef R3
    __syncthreads();                        // B4 (WAR)

    // ---- FFT64 over b (b = 8u+v), fixed q = l ----
    FFT8N(g)
#define W4(t) xch[512*v + 64*t + l] = g##t;
    FOR8(W4)
#undef W4
    __syncthreads();                        // B5
#define R4(vv) g##vv = xch[512*vv + 64*v + l];
    FOR8(R4)
#undef R4
    __syncthreads();                        // B6 (WAR)

    TWCHAIN(g, wv)
    FFT8N(g)                                // -> X[512s + 64v + l] in g_s

    // pane [p][q] (pad 65), p = 8s+v, q = l
#define W5(s) xch[520*s + 65*v + l] = g##s;
    FOR8(W5)
#undef W5
    __syncthreads();                        // B7

    // epilogue: conj-split + expk.  k = 512s + 64v + l, partner m = (4096-k)&4095
    float* outA = out + (size_t)r0 * L;
    float* outB = outA + L;
    float2 e; __sincosf((float)(64*v + l) * 3.8349519697141029e-4f, &e.y, &e.x); // pi k0/8192
    const float2 ST = make_float2(0.98078528040323045f, 0.19509032201612827f);   // e^{i pi/16}
#define EP5(s) { \
        const int k = 512*s + 64*v + l; \
        const int m = (4096 - k) & 4095; \
        float2 Zk = g##s; \
        float2 Zm = xch[(m >> 6) * 65 + (m & 63)]; \
        float vax = 0.5f*(Zk.x + Zm.x), vay = 0.5f*(Zk.y - Zm.y); \
        float vbx = 0.5f*(Zk.y + Zm.y), vby = 0.5f*(Zm.x - Zk.x); \
        outA[k] = vax*e.x + vay*e.y; \
        outB[k] = vbx*e.x + vby*e.y; \
        e = cmul(e, ST); }
    FOR8(EP5)
#undef EP5
}

// ---------------- K2a: cooperative column pass, step 1 (unchanged) ----------------
__global__ __launch_bounds__(512)
void fft64_col_a2(const float* __restrict__ Y, float* __restrict__ ws) {
    __shared__ float2 xch[4096];            // [v][t][c], 32 KB
    const int c = threadIdx.x & 63;
    const int v = threadIdx.x >> 6;         // 0..7
    const int b = blockIdx.x;               // 0..63
    const int T = blockIdx.y;               // 0..31
    const int ca = T * 128 + c;
    const int cb = ca + 64;

#define LDA(u) float2 g##u; { \
        const int aa = 8 * u + v; \
        const int row = (u < 4) ? (128 * aa + 2 * b) : (8191 - 128 * aa - 2 * b); \
        const float* rp = Y + (size_t)row * L; \
        g##u = make_float2(rp[ca], rp[cb]); }
    FOR8(LDA)
#undef LDA

    FFT8N(g)                                // over u -> G[t][v] in g_t

#define WRA(t) xch[v * 512 + t * 64 + c] = g##t;
    FOR8(WRA)
#undef WRA
    __syncthreads();
#define RDA(vv) g##vv = xch[vv * 512 + v * 64 + c];
    FOR8(RDA)
#undef RDA

    float2 wv; __sincosf((float)v * -0.09817477042468103f, &wv.y, &wv.x); // -2pi v/64
    TWCHAIN(g, wv)

    FFT8N(g)                                // -> Z[q], q = 8s+v, in g_s

    float2 mw, ms;
    __sincosf((float)(b * v) * -1.5339807878856412e-3f, &mw.y, &mw.x);
    __sincosf((float)b * -1.2271846303085130e-2f, &ms.y, &ms.x);   // -pi b/256
    float2* wp = reinterpret_cast<float2*>(ws) + (size_t)b * 2048 + (size_t)T * 64 + c;
#define STA(s) { \
        g##s = cmul(g##s, mw); \
        wp[(size_t)(8 * s + v) * 131072] = g##s; \
        mw = cmul(mw, ms); }
    FOR8(STA)
#undef STA
}

// ---------------- K2b: column pass step 2, linearity form (unchanged) ----------------
__global__ __launch_bounds__(512)
void fft64_col_b3(const float* __restrict__ wsf, float* __restrict__ out) {
    __shared__ float2 xch[8192];            // [0,4096)=X pane, [4096,8192)=G pane
    const int c  = threadIdx.x & 63;
    const int v  = threadIdx.x >> 6;        // 0..7
    const int qa = blockIdx.x;              // 0..31
    const int T  = blockIdx.y;              // 0..31
    const int q  = qa;
    const int q2 = (qa == 0) ? 32 : 64 - qa;

    const float2* wsc = reinterpret_cast<const float2*>(wsf);
    const size_t cbase = (size_t)T * 64 + c;

#define LDH(u) \
    float2 ha##u = wsc[(size_t)q  * 131072 + (size_t)(8*u+v) * 2048 + cbase]; \
    float2 hp##u = wsc[(size_t)q2 * 131072 + (size_t)(8*u+v) * 2048 + cbase];
    FOR8(LDH)
#undef LDH

    float2 wv; __sincosf((float)v * -0.09817477042468103f, &wv.y, &wv.x);

    // ---- FFT64 #1: Gq = FFT64_b(H[q]) ----
    FFT8N(ha)
#define W1(k) xch[v * 512 + k * 64 + c] = ha##k;
    FOR8(W1)
#undef W1
    __syncthreads();                        // bar1
#define DECLG(i) float2 g##i;
    FOR8(DECLG)
#undef DECLG
#define R1b(vv) g##vv = xch[vv * 512 + v * 64 + c];
    FOR8(R1b)
#undef R1b
    TWCHAIN(g, wv)
    FFT8N(g)                                // -> Gq[8a+v] in g_a

#define SV(a) float2 gq##a = g##a; xch[4096 + (8*a + v) * 64 + c] = g##a;
    FOR8(SV)
#undef SV
    __syncthreads();                        // bar2

    // ---- FFT64 #2: Gq2 = FFT64_b(H[q2]) ----
    FFT8N(hp)
#define W2b(k) xch[v * 512 + k * 64 + c] = hp##k;
    FOR8(W2b)
#undef W2b
    __syncthreads();                        // bar3
#define R2b(vv) g##vv = xch[vv * 512 + v * 64 + c];
    FOR8(R2b)
#undef R2b
    TWCHAIN(g, wv)
    FFT8N(g)                                // -> Gq2[8a+v] in g_a
    __syncthreads();                        // bar4
#define W3b(a) xch[(8*a + v) * 64 + c] = g##a;
    FOR8(W3b)
#undef W3b
    __syncthreads();                        // bar5

    const float2 STEP = make_float2(0.98078528040323045f, 0.19509032201612827f); // e^{+i pi/16}
    float2 eq, eq2;
    __sincosf((float)(64 * v + q ) * 3.8349519697141029e-4f, &eq.y,  &eq.x);
    __sincosf((float)(64 * v + q2) * 3.8349519697141029e-4f, &eq2.y, &eq2.x);
    const int colA = T * 128 + c;

#define CMB(a) { \
    const int p_ = 8 * a + v; \
    float2 rq  = (qa == 0) ? xch[4096 + (((64 - p_) & 63) * 64) + c] \
                           : xch[(63 - p_) * 64 + c]; \
    float2 rq2 = (qa == 0) ? xch[(63 - p_) * 64 + c] \
                           : xch[4096 + (63 - p_) * 64 + c]; \
    float FAx = 0.5f * (gq##a.x + rq.x), FAy = 0.5f * (gq##a.y - rq.y); \
    float FBx = 0.5f * (gq##a.y + rq.y), FBy = 0.5f * (rq.x - gq##a.x); \
    size_t rowq = (size_t)(512 * a + 64 * v + q) * L; \
    out[rowq + colA]      = FAx * eq.x + FAy * eq.y; \
    out[rowq + colA + 64] = FBx * eq.x + FBy * eq.y; \
    float GAx = 0.5f * (g##a.x + rq2.x), GAy = 0.5f * (g##a.y - rq2.y); \
    float GBx = 0.5f * (g##a.y + rq2.y), GBy = 0.5f * (rq2.x - g##a.x); \
    size_t rowq2 = (size_t)(512 * a + 64 * v + q2) * L; \
    out[rowq2 + colA]      = GAx * eq2.x + GAy * eq2.y; \
    out[rowq2 + colA + 64] = GBx * eq2.x + GBy * eq2.y; \
    eq = cmul(eq, STEP); eq2 = cmul(eq2, STEP); }
    FOR8(CMB)
#undef CMB
}

extern "C" void kernel_launch(void* const* d_in, const int* in_sizes, int n_in,
                              void* d_out, int out_size, void* d_ws, size_t ws_size,
                              hipStream_t stream) {
    const float* x = (const float*)d_in[0];
    float* out = (float*)d_out;
    float* ws  = (float*)d_ws;   // needs 64 MB

    dct_rows4_kernel<<<L / 2, 512, 0, stream>>>(x, out);        // rows: x -> Y(out)
    fft64_col_a2<<<dim3(64, 32), 512, 0, stream>>>(out, ws);    // Y -> H(ws)
    fft64_col_b3<<<dim3(32, 32), 512, 0, stream>>>(ws, out);    // H -> final(out)
}